// Round 4
// baseline (5528.608 us; speedup 1.0000x reference)
//
#include <hip/hip_runtime.h>

using u16 = unsigned short;
using u32 = unsigned int;

__device__ __forceinline__ float bf2f(u16 v) { return __uint_as_float(((u32)v) << 16); }
__device__ __forceinline__ u16 f2bf(float f) {
  u32 u = __float_as_uint(f);
  u += 0x7fffu + ((u >> 16) & 1u);   // RNE
  return (u16)(u >> 16);
}

// ---------------------------------------------------------------------------
// h = x @ W + b, fused with 4 attention dot-products.
// SIMPLE FORM: 512 threads = 4 nodes x 128 cols, one output element per
// thread, W read from global (L2-resident, coalesced).
// ---------------------------------------------------------------------------
__global__ __launch_bounds__(512) void proj_kernel(
    const float* __restrict__ x, const float* __restrict__ W,
    const float* __restrict__ bias,
    const float* __restrict__ att0, const float* __restrict__ att1,
    const float* __restrict__ att2, const float* __restrict__ att3,
    u16* __restrict__ h_out,
    float* __restrict__ al0, float* __restrict__ al1,
    float* __restrict__ al2, float* __restrict__ al3,
    int N)
{
  __shared__ float xrow[4][128];
  __shared__ float hrow[4][128];
  __shared__ float attl[4][128];
  __shared__ float bl[128];
  const int tid = threadIdx.x;
  const int n0 = blockIdx.x * 4;
  const int r = tid >> 7, c = tid & 127;

  xrow[r][c] = (n0 + r < N) ? x[(size_t)(n0 + r) * 128 + c] : 0.f;
  {
    int a = tid >> 7, p = tid & 127;   // 512 threads = 4*128 att entries
    const float* ap = (a == 0) ? att0 : (a == 1) ? att1 : (a == 2) ? att2 : att3;
    attl[a][p] = ap[p];
  }
  if (tid < 128) bl[tid] = bias[tid];
  __syncthreads();

  float acc = bl[c];
#pragma unroll 8
  for (int k = 0; k < 128; ++k) acc += xrow[r][k] * W[k * 128 + c];
  hrow[r][c] = acc;
  const int node = n0 + r;
  if (node < N) h_out[(size_t)node * 128 + c] = f2bf(acc);
  __syncthreads();

  if (tid < 128) {   // 4 nodes x 8 heads x 4 att-vectors = 128 tasks
    int a = tid & 3, hd = (tid >> 2) & 7, rr = tid >> 5;
    int nn = n0 + rr;
    if (nn < N) {
      float s = 0.f;
#pragma unroll
      for (int j = 0; j < 16; ++j) s += hrow[rr][hd * 16 + j] * attl[a][hd * 16 + j];
      float* alp = (a == 0) ? al0 : (a == 1) ? al1 : (a == 2) ? al2 : al3;
      alp[(size_t)nn * 8 + hd] = s;
    }
  }
}

// ---------------------------------------------------------------------------
// per-edge: ex = exp(leaky_relu(alpha_s[src] + alpha_d[dst])); denom[dst] += ex
// (softmax is shift-invariant; logits are O(6) so no max-subtraction needed)
// ---------------------------------------------------------------------------
__global__ __launch_bounds__(256) void edge_softmax_kernel(
    const int* __restrict__ ei, int E,
    const float* __restrict__ aS, const float* __restrict__ aD,
    float* __restrict__ ea, float* __restrict__ denom)
{
  int e = blockIdx.x * 256 + threadIdx.x;
  if (e >= E) return;
  int s = ei[e], d = ei[E + e];
  float4 s0 = *(const float4*)&aS[(size_t)s * 8];
  float4 s1 = *(const float4*)&aS[(size_t)s * 8 + 4];
  float4 d0 = *(const float4*)&aD[(size_t)d * 8];
  float4 d1 = *(const float4*)&aD[(size_t)d * 8 + 4];
  float l[8] = {s0.x + d0.x, s0.y + d0.y, s0.z + d0.z, s0.w + d0.w,
                s1.x + d1.x, s1.y + d1.y, s1.z + d1.z, s1.w + d1.w};
  float ex[8];
#pragma unroll
  for (int h = 0; h < 8; ++h) {
    float v = l[h] > 0.f ? l[h] : 0.2f * l[h];
    ex[h] = expf(v);
  }
  *(float4*)&ea[(size_t)e * 8]     = make_float4(ex[0], ex[1], ex[2], ex[3]);
  *(float4*)&ea[(size_t)e * 8 + 4] = make_float4(ex[4], ex[5], ex[6], ex[7]);
#pragma unroll
  for (int h = 0; h < 8; ++h) atomicAdd(&denom[(size_t)d * 8 + h], ex[h]);
}

// ---------------------------------------------------------------------------
// o[dst] += (ex/denom) * h_src[src]   -- 32 lanes per edge, 4 dims per lane
// ---------------------------------------------------------------------------
__global__ __launch_bounds__(256) void edge_aggregate_kernel(
    const int* __restrict__ ei, int E,
    const float* __restrict__ ea, const float* __restrict__ denom,
    const u16* __restrict__ hsrc, float* __restrict__ o)
{
  int t = blockIdx.x * 256 + threadIdx.x;
  int e = t >> 5;
  if (e >= E) return;
  int l = t & 31;
  int s = ei[e], d = ei[E + e];
  int head = l >> 2, col = l << 2;
  float wgt = ea[(size_t)e * 8 + head] / (denom[(size_t)d * 8 + head] + 1e-16f);
  ushort4 hv = *(const ushort4*)&hsrc[(size_t)s * 128 + col];
  float* op = &o[(size_t)d * 128 + col];
  atomicAdd(op + 0, wgt * bf2f(hv.x));
  atomicAdd(op + 1, wgt * bf2f(hv.y));
  atomicAdd(op + 2, wgt * bf2f(hv.z));
  atomicAdd(op + 3, wgt * bf2f(hv.w));
}

// ---------------------------------------------------------------------------
// score += sum_n tanh(relu(o[n]) @ Wk + bk) . q
// SIMPLE FORM: 512 threads = 4 nodes x 128 cols, Wk from global (L2-resident).
// ---------------------------------------------------------------------------
__global__ __launch_bounds__(512) void sem_score_kernel(
    const float* __restrict__ o, const float* __restrict__ Wk,
    const float* __restrict__ bk, const float* __restrict__ q,
    float* __restrict__ score_slot, int N)
{
  __shared__ float orow[4][128];
  __shared__ float bl[128], ql[128];
  __shared__ float red[8];
  const int tid = threadIdx.x;
  const int n0 = blockIdx.x * 4;
  const int r = tid >> 7, c = tid & 127;

  float v = (n0 + r < N) ? o[(size_t)(n0 + r) * 128 + c] : 0.f;
  orow[r][c] = fmaxf(v, 0.f);
  if (tid < 128) { bl[tid] = bk[tid]; ql[tid] = q[tid]; }
  __syncthreads();

  float acc = bl[c];
#pragma unroll 8
  for (int k = 0; k < 128; ++k) acc += orow[r][k] * Wk[k * 128 + c];
  float p = (n0 + r < N) ? tanhf(acc) * ql[c] : 0.f;
#pragma unroll
  for (int off = 32; off > 0; off >>= 1) p += __shfl_down(p, off);
  if ((tid & 63) == 0) red[tid >> 6] = p;
  __syncthreads();
  if (tid == 0) {
    float s = 0.f;
#pragma unroll
    for (int i = 0; i < 8; ++i) s += red[i];
    atomicAdd(score_slot, s);
  }
}

__global__ void attn_kernel(const float* __restrict__ scores, float* __restrict__ attn,
                            float invN)
{
  if (threadIdx.x == 0) {
#pragma unroll
    for (int t = 0; t < 2; ++t) {
      float s0 = scores[2 * t] * invN, s1 = scores[2 * t + 1] * invN;
      float m = fmaxf(s0, s1);
      float e0 = expf(s0 - m), e1 = expf(s1 - m);
      float inv = 1.f / (e0 + e1);
      attn[2 * t] = e0 * inv; attn[2 * t + 1] = e1 * inv;
    }
  }
}

// ---------------------------------------------------------------------------
// BN stats over nodes of c = attn0*relu(o0) + attn1*relu(o1)
// ---------------------------------------------------------------------------
__global__ __launch_bounds__(256) void bn_stats_kernel(
    const float* __restrict__ o0, const float* __restrict__ o1,
    const float* __restrict__ attn, float* __restrict__ sums, int N, int R)
{
  float a0 = attn[0], a1 = attn[1];
  int f = threadIdx.x & 127, half = threadIdx.x >> 7;
  int rend = min((blockIdx.x + 1) * R, N);
  float s = 0.f, sq = 0.f;
  for (int r = blockIdx.x * R + half; r < rend; r += 2) {
    size_t idx = (size_t)r * 128 + f;
    float c = a0 * fmaxf(o0[idx], 0.f) + a1 * fmaxf(o1[idx], 0.f);
    s += c; sq += c * c;
  }
  __shared__ float sm[2][128];
  __shared__ float sm2[2][128];
  sm[half][f] = s; sm2[half][f] = sq;
  __syncthreads();
  if (half == 0) {
    atomicAdd(&sums[f], s + sm[1][f]);
    atomicAdd(&sums[128 + f], sq + sm2[1][f]);
  }
}

// ---------------------------------------------------------------------------
// out (FLOAT32) = gamma * (c - mu) / sqrt(var + eps) + beta
// ---------------------------------------------------------------------------
__global__ __launch_bounds__(256) void bn_final_kernel(
    const float* __restrict__ o0, const float* __restrict__ o1,
    const float* __restrict__ attn, const float* __restrict__ sums,
    const float* __restrict__ gamma, const float* __restrict__ beta,
    float* __restrict__ out, int N)
{
  __shared__ float scale[128], shift[128];
  if (threadIdx.x < 128) {
    int f = threadIdx.x;
    float invN = 1.f / (float)N;
    float mu = sums[f] * invN;
    float var = fmaxf(sums[128 + f] * invN - mu * mu, 0.f);
    float rs = rsqrtf(var + 1e-5f);
    float g = gamma[f] * rs;
    scale[f] = g;
    shift[f] = beta[f] - mu * g;
  }
  float a0 = attn[0], a1 = attn[1];
  __syncthreads();
  size_t total = (size_t)N * 128;
  for (size_t base = ((size_t)blockIdx.x * 256 + threadIdx.x) * 8; base < total;
       base += (size_t)gridDim.x * 2048) {
    int f0 = (int)(base & 127);
    float4 p0 = *(const float4*)&o0[base];
    float4 p1 = *(const float4*)&o0[base + 4];
    float4 q0 = *(const float4*)&o1[base];
    float4 q1 = *(const float4*)&o1[base + 4];
    float4 r0, r1;
    r0.x = (a0 * fmaxf(p0.x, 0.f) + a1 * fmaxf(q0.x, 0.f)) * scale[f0 + 0] + shift[f0 + 0];
    r0.y = (a0 * fmaxf(p0.y, 0.f) + a1 * fmaxf(q0.y, 0.f)) * scale[f0 + 1] + shift[f0 + 1];
    r0.z = (a0 * fmaxf(p0.z, 0.f) + a1 * fmaxf(q0.z, 0.f)) * scale[f0 + 2] + shift[f0 + 2];
    r0.w = (a0 * fmaxf(p0.w, 0.f) + a1 * fmaxf(q0.w, 0.f)) * scale[f0 + 3] + shift[f0 + 3];
    r1.x = (a0 * fmaxf(p1.x, 0.f) + a1 * fmaxf(q1.x, 0.f)) * scale[f0 + 4] + shift[f0 + 4];
    r1.y = (a0 * fmaxf(p1.y, 0.f) + a1 * fmaxf(q1.y, 0.f)) * scale[f0 + 5] + shift[f0 + 5];
    r1.z = (a0 * fmaxf(p1.z, 0.f) + a1 * fmaxf(q1.z, 0.f)) * scale[f0 + 6] + shift[f0 + 6];
    r1.w = (a0 * fmaxf(p1.w, 0.f) + a1 * fmaxf(q1.w, 0.f)) * scale[f0 + 7] + shift[f0 + 7];
    *(float4*)&out[base] = r0;
    *(float4*)&out[base + 4] = r1;
  }
}

extern "C" void kernel_launch(void* const* d_in, const int* in_sizes, int n_in,
                              void* d_out, int out_size, void* d_ws, size_t ws_size,
                              hipStream_t stream)
{
  const float* x_a      = (const float*)d_in[0];
  const float* x_b      = (const float*)d_in[1];
  const int* ei_ab      = (const int*)d_in[2];
  const int* ei_ba      = (const int*)d_in[3];
  const int* ei_aa      = (const int*)d_in[4];
  const int* ei_bb      = (const int*)d_in[5];
  const float* W_a      = (const float*)d_in[6];
  const float* b_a      = (const float*)d_in[7];
  const float* W_b      = (const float*)d_in[8];
  const float* b_b      = (const float*)d_in[9];
  const float* att_ab_s = (const float*)d_in[10];
  const float* att_ab_d = (const float*)d_in[11];
  const float* att_ba_s = (const float*)d_in[12];
  const float* att_ba_d = (const float*)d_in[13];
  const float* att_aa_s = (const float*)d_in[14];
  const float* att_aa_d = (const float*)d_in[15];
  const float* att_bb_s = (const float*)d_in[16];
  const float* att_bb_d = (const float*)d_in[17];
  const float* Wk       = (const float*)d_in[18];
  const float* bk       = (const float*)d_in[19];
  const float* q        = (const float*)d_in[20];
  const float* gamma    = (const float*)d_in[21];
  const float* beta     = (const float*)d_in[22];

  const int N = in_sizes[0] / 128;
  const int E = in_sizes[2] / 2;

  char* wp = (char*)d_ws;
  auto alloc = [&](size_t bytes) -> void* {
    void* p = (void*)wp;
    wp += (bytes + 255) & ~(size_t)255;
    return p;
  };
  u16* h_a = (u16*)alloc((size_t)N * 128 * 2);
  u16* h_b = (u16*)alloc((size_t)N * 128 * 2);
  float* A[8];
  for (int i = 0; i < 8; ++i) A[i] = (float*)alloc((size_t)N * 8 * 4);
  float* ea    = (float*)alloc((size_t)E * 8 * 4);
  float* denom = (float*)alloc((size_t)N * 8 * 4);
  float* o_ab = (float*)alloc((size_t)N * 128 * 4);   // 4 o-arrays contiguous
  float* o_ba = (float*)alloc((size_t)N * 128 * 4);
  float* o_aa = (float*)alloc((size_t)N * 128 * 4);
  float* o_bb = (float*)alloc((size_t)N * 128 * 4);
  float* scores = (float*)alloc(16);
  float* attn   = (float*)alloc(16);
  float* sums_a = (float*)alloc(1024);
  float* sums_b = (float*)alloc(1024);
  if ((size_t)(wp - (char*)d_ws) > ws_size) return;  // ws too small: bail loudly

  hipMemsetAsync(o_ab, 0, (size_t)N * 128 * 4 * 4, stream);
  hipMemsetAsync(scores, 0, 2560, stream);           // scores+attn+sums (contiguous)

  const int gproj = (N + 3) / 4;
  proj_kernel<<<gproj, 512, 0, stream>>>(x_a, W_a, b_a, att_ab_s, att_aa_s, att_aa_d,
                                         att_ba_d, h_a, A[0], A[1], A[2], A[3], N);
  proj_kernel<<<gproj, 512, 0, stream>>>(x_b, W_b, b_b, att_ab_d, att_bb_s, att_bb_d,
                                         att_ba_s, h_b, A[4], A[5], A[6], A[7], N);

  const int gA = (E + 255) / 256;
  const int gB = (E * 32 + 255) / 256;
  struct Rel { const int* ei; const float* aS; const float* aD; const u16* h; float* o; };
  Rel rels[4] = {
    {ei_ab, A[0], A[4], h_a, o_ab},
    {ei_ba, A[7], A[3], h_b, o_ba},
    {ei_aa, A[1], A[2], h_a, o_aa},
    {ei_bb, A[5], A[6], h_b, o_bb},
  };
  for (int r = 0; r < 4; ++r) {
    hipMemsetAsync(denom, 0, (size_t)N * 8 * 4, stream);
    edge_softmax_kernel<<<gA, 256, 0, stream>>>(rels[r].ei, E, rels[r].aS, rels[r].aD,
                                                ea, denom);
    edge_aggregate_kernel<<<gB, 256, 0, stream>>>(rels[r].ei, E, ea, denom,
                                                  rels[r].h, rels[r].o);
  }

  sem_score_kernel<<<gproj, 512, 0, stream>>>(o_ba, Wk, bk, q, scores + 0, N);
  sem_score_kernel<<<gproj, 512, 0, stream>>>(o_aa, Wk, bk, q, scores + 1, N);
  sem_score_kernel<<<gproj, 512, 0, stream>>>(o_ab, Wk, bk, q, scores + 2, N);
  sem_score_kernel<<<gproj, 512, 0, stream>>>(o_bb, Wk, bk, q, scores + 3, N);
  attn_kernel<<<1, 64, 0, stream>>>(scores, attn, 1.0f / (float)N);

  const int R = (N + 255) / 256;
  bn_stats_kernel<<<256, 256, 0, stream>>>(o_ba, o_aa, attn + 0, sums_a, N, R);
  bn_stats_kernel<<<256, 256, 0, stream>>>(o_ab, o_bb, attn + 2, sums_b, N, R);

  float* out = (float*)d_out;
  bn_final_kernel<<<2048, 256, 0, stream>>>(o_ba, o_aa, attn + 0, sums_a, gamma, beta,
                                            out, N);
  bn_final_kernel<<<2048, 256, 0, stream>>>(o_ab, o_bb, attn + 2, sums_b, gamma, beta,
                                            out + (size_t)N * 128, N);
}

// Round 5
// 1336.318 us; speedup vs baseline: 4.1372x; 4.1372x over previous
//
#include <hip/hip_runtime.h>

using u16 = unsigned short;
using u32 = unsigned int;

__device__ __forceinline__ float bf2f(u16 v) { return __uint_as_float(((u32)v) << 16); }
__device__ __forceinline__ float blo(u32 u) { return __uint_as_float(u << 16); }
__device__ __forceinline__ float bhi(u32 u) { return __uint_as_float(u & 0xffff0000u); }
__device__ __forceinline__ u16 f2bf(float f) {
  u32 u = __float_as_uint(f);
  u += 0x7fffu + ((u >> 16) & 1u);   // RNE
  return (u16)(u >> 16);
}

// ---------------------------------------------------------------------------
// h = x @ W + b (f32 in), fused with 4 attention dot-products.
// Register-blocked: 256 thr = 32 nodes x 8 heads, 16 accs/thread,
// W packed bf16 in LDS (2 x ds_read_b128 per k -> 16 FMA).
// ---------------------------------------------------------------------------
__global__ __launch_bounds__(256) void proj_kernel(
    const float* __restrict__ x, const float* __restrict__ W,
    const float* __restrict__ bias,
    const float* __restrict__ att0, const float* __restrict__ att1,
    const float* __restrict__ att2, const float* __restrict__ att3,
    u16* __restrict__ h_out,
    float* __restrict__ al0, float* __restrict__ al1,
    float* __restrict__ al2, float* __restrict__ al3,
    int N)
{
  __shared__ uint4 Wl4[2048];        // W as packed bf16 [128 rows][16 uint4]
  __shared__ float4 xs4[32 * 33];    // x tile f32 [32][132] padded
  __shared__ float attl[4][128];
  __shared__ float bl[128];
  const int tid = threadIdx.x;
  const int nb = blockIdx.x * 32;

  const float4* Wg = (const float4*)W;
#pragma unroll
  for (int i = 0; i < 8; ++i) {
    int o = tid + 256 * i;
    float4 f0 = Wg[o * 2];
    float4 f1 = Wg[o * 2 + 1];
    uint4 pv;
    pv.x = (u32)f2bf(f0.x) | ((u32)f2bf(f0.y) << 16);
    pv.y = (u32)f2bf(f0.z) | ((u32)f2bf(f0.w) << 16);
    pv.z = (u32)f2bf(f1.x) | ((u32)f2bf(f1.y) << 16);
    pv.w = (u32)f2bf(f1.z) | ((u32)f2bf(f1.w) << 16);
    Wl4[o] = pv;
  }
  {
    const float4* xg = (const float4*)(x + (size_t)nb * 128);
#pragma unroll
    for (int i = 0; i < 4; ++i) {
      int idx = tid + 256 * i;                // 0..1023
      int row = idx >> 5, part = idx & 31;
      float4 v = make_float4(0.f, 0.f, 0.f, 0.f);
      if (nb + row < N) v = xg[row * 32 + part];
      xs4[row * 33 + part] = v;
    }
  }
#pragma unroll
  for (int i = 0; i < 2; ++i) {
    int idx = tid + 256 * i;
    int a = idx >> 7, p = idx & 127;
    const float* ap = (a == 0) ? att0 : (a == 1) ? att1 : (a == 2) ? att2 : att3;
    attl[a][p] = ap[p];
  }
  if (tid < 128) bl[tid] = bias[tid];
  __syncthreads();

  const int nl = tid >> 3, hd = tid & 7, c0 = hd << 4;
  const float* xs = (const float*)xs4;
  float acc[16];
#pragma unroll
  for (int j = 0; j < 16; ++j) acc[j] = bl[c0 + j];

#pragma unroll 4
  for (int k = 0; k < 128; ++k) {
    float xv = xs[nl * 132 + k];
    uint4 w0 = Wl4[(k << 4) + (hd << 1)];
    uint4 w1 = Wl4[(k << 4) + (hd << 1) + 1];
    acc[0]  += xv * blo(w0.x);  acc[1]  += xv * bhi(w0.x);
    acc[2]  += xv * blo(w0.y);  acc[3]  += xv * bhi(w0.y);
    acc[4]  += xv * blo(w0.z);  acc[5]  += xv * bhi(w0.z);
    acc[6]  += xv * blo(w0.w);  acc[7]  += xv * bhi(w0.w);
    acc[8]  += xv * blo(w1.x);  acc[9]  += xv * bhi(w1.x);
    acc[10] += xv * blo(w1.y);  acc[11] += xv * bhi(w1.y);
    acc[12] += xv * blo(w1.z);  acc[13] += xv * bhi(w1.z);
    acc[14] += xv * blo(w1.w);  acc[15] += xv * bhi(w1.w);
  }

  const int node = nb + nl;
  if (node < N) {
    float* als[4] = {al0, al1, al2, al3};
#pragma unroll
    for (int a = 0; a < 4; ++a) {
      float s = 0.f;
#pragma unroll
      for (int j = 0; j < 16; ++j) s += acc[j] * attl[a][c0 + j];
      als[a][(size_t)node * 8 + hd] = s;
    }
    uint4 hv0, hv1;
    hv0.x = (u32)f2bf(acc[0])  | ((u32)f2bf(acc[1])  << 16);
    hv0.y = (u32)f2bf(acc[2])  | ((u32)f2bf(acc[3])  << 16);
    hv0.z = (u32)f2bf(acc[4])  | ((u32)f2bf(acc[5])  << 16);
    hv0.w = (u32)f2bf(acc[6])  | ((u32)f2bf(acc[7])  << 16);
    hv1.x = (u32)f2bf(acc[8])  | ((u32)f2bf(acc[9])  << 16);
    hv1.y = (u32)f2bf(acc[10]) | ((u32)f2bf(acc[11]) << 16);
    hv1.z = (u32)f2bf(acc[12]) | ((u32)f2bf(acc[13]) << 16);
    hv1.w = (u32)f2bf(acc[14]) | ((u32)f2bf(acc[15]) << 16);
    uint4* hp = (uint4*)(h_out + (size_t)node * 128 + c0);
    hp[0] = hv0; hp[1] = hv1;
  }
}

// ------------------------- CSR build ---------------------------------------
__global__ __launch_bounds__(256) void hist_kernel(const int* __restrict__ dst, int E,
                                                   int* __restrict__ cnt)
{
  int e = blockIdx.x * 256 + threadIdx.x;
  if (e < E) atomicAdd(&cnt[dst[e]], 1);
}

// scan1: per-block (256 thr x 8) exclusive scan in-place, emit block sums
__global__ __launch_bounds__(256) void scan1_kernel(int* __restrict__ data, int M,
                                                    int* __restrict__ bsum)
{
  __shared__ int ls[256];
  const int tid = threadIdx.x;
  const int base = blockIdx.x * 2048 + tid * 8;
  int v[8]; int s = 0;
#pragma unroll
  for (int j = 0; j < 8; ++j) v[j] = (base + j < M) ? data[base + j] : 0;
#pragma unroll
  for (int j = 0; j < 8; ++j) { int t = v[j]; v[j] = s; s += t; }
  ls[tid] = s;
  __syncthreads();
  for (int off = 1; off < 256; off <<= 1) {
    int t = (tid >= off) ? ls[tid - off] : 0;
    __syncthreads();
    ls[tid] += t;
    __syncthreads();
  }
  int texcl = ls[tid] - s;
#pragma unroll
  for (int j = 0; j < 8; ++j)
    if (base + j < M) data[base + j] = v[j] + texcl;
  if (tid == 255) bsum[blockIdx.x] = ls[255];
}

// scan2: one block turns bsum (G1 <= 256) into its exclusive scan
__global__ __launch_bounds__(256) void scan2_kernel(int* __restrict__ bsum, int G1)
{
  __shared__ int ls[256];
  const int tid = threadIdx.x;
  int v = (tid < G1) ? bsum[tid] : 0;
  ls[tid] = v;
  __syncthreads();
  for (int off = 1; off < 256; off <<= 1) {
    int t = (tid >= off) ? ls[tid - off] : 0;
    __syncthreads();
    ls[tid] += t;
    __syncthreads();
  }
  if (tid < G1) bsum[tid] = ls[tid] - v;
}

// scan3: add block offset; also mirror into cursor
__global__ __launch_bounds__(256) void scan3_kernel(int* __restrict__ data,
                                                    const int* __restrict__ bsum, int M,
                                                    int* __restrict__ cursor)
{
  const int add = bsum[blockIdx.x];
  const int base = blockIdx.x * 2048 + threadIdx.x * 8;
#pragma unroll
  for (int j = 0; j < 8; ++j) {
    int i = base + j;
    if (i < M) { int t = data[i] + add; data[i] = t; cursor[i] = t; }
  }
}

__global__ __launch_bounds__(256) void scatter_kernel(
    const int* __restrict__ e0, const int* __restrict__ e1,
    const int* __restrict__ e2, const int* __restrict__ e3,
    int E, int N, int* __restrict__ cursor, int* __restrict__ ssrc)
{
  const int r = blockIdx.y;
  const int* ei = (r == 0) ? e0 : (r == 1) ? e1 : (r == 2) ? e2 : e3;
  int e = blockIdx.x * 256 + threadIdx.x;
  if (e >= E) return;
  int s = ei[e], d = ei[E + e];
  int p = atomicAdd(&cursor[r * N + d], 1);
  ssrc[p] = s;
}

// ---------------------------------------------------------------------------
// Fused segment-softmax + aggregate: 1 wave per dst node.
// o[n] = (sum_e ex_e * h[src_e]) / (sum_e ex_e + 1e-16)
// ---------------------------------------------------------------------------
__global__ __launch_bounds__(256) void aggregate_kernel(
    const int* __restrict__ off, const int* __restrict__ ssrc,
    const float* __restrict__ aS0, const float* __restrict__ aS1,
    const float* __restrict__ aS2, const float* __restrict__ aS3,
    const float* __restrict__ aD0, const float* __restrict__ aD1,
    const float* __restrict__ aD2, const float* __restrict__ aD3,
    const u16* __restrict__ h0, const u16* __restrict__ h1,
    const u16* __restrict__ h2, const u16* __restrict__ h3,
    float* __restrict__ o0, float* __restrict__ o1,
    float* __restrict__ o2, float* __restrict__ o3,
    int N, int E)
{
  const int r = blockIdx.y;
  const float* aS = (r == 0) ? aS0 : (r == 1) ? aS1 : (r == 2) ? aS2 : aS3;
  const float* aD = (r == 0) ? aD0 : (r == 1) ? aD1 : (r == 2) ? aD2 : aD3;
  const u16*   h  = (r == 0) ? h0  : (r == 1) ? h1  : (r == 2) ? h2  : h3;
  float*       o  = (r == 0) ? o0  : (r == 1) ? o1  : (r == 2) ? o2  : o3;

  const int wave = threadIdx.x >> 6, lane = threadIdx.x & 63;
  const int n = blockIdx.x * 4 + wave;
  if (n >= N) return;
  const int head = lane >> 3;
  const int idx = r * N + n;
  const int p0 = off[idx];
  const int p1 = (idx + 1 < 4 * N) ? off[idx + 1] : 4 * E;
  const float aDv = aD[(size_t)n * 8 + head];
  const u32* h32 = (const u32*)h;

  float acc0 = 0.f, acc1 = 0.f, den = 0.f;
  for (int p = p0; p < p1; ++p) {
    int s = ssrc[p];
    float logit = aS[(size_t)s * 8 + head] + aDv;
    float w = expf(logit > 0.f ? logit : 0.2f * logit);
    den += w;
    u32 hv = h32[(size_t)s * 64 + lane];
    acc0 += w * blo(hv);
    acc1 += w * bhi(hv);
  }
  float inv = 1.f / (den + 1e-16f);
  float2 res = make_float2(acc0 * inv, acc1 * inv);
  *(float2*)&o[(size_t)n * 128 + lane * 2] = res;
}

// ---------------------------------------------------------------------------
// score += sum_n tanh(relu(o[n]) @ Wk + bk) . q  — register-blocked
// ---------------------------------------------------------------------------
__global__ __launch_bounds__(256) void sem_score_kernel(
    const float* __restrict__ o, const float* __restrict__ Wk,
    const float* __restrict__ bk, const float* __restrict__ q,
    float* __restrict__ score_slot, int N)
{
  __shared__ uint4 Wl4[2048];       // Wk packed bf16
  __shared__ float4 os4[32 * 33];   // [32][132] f32, padded
  __shared__ float bl[128], ql[128];
  __shared__ float red[4];
  const int tid = threadIdx.x;
  const int nb = blockIdx.x * 32;

  const float4* Wg = (const float4*)Wk;
#pragma unroll
  for (int i = 0; i < 8; ++i) {
    int o4 = tid + 256 * i;
    float4 f0 = Wg[o4 * 2];
    float4 f1 = Wg[o4 * 2 + 1];
    uint4 pv;
    pv.x = (u32)f2bf(f0.x) | ((u32)f2bf(f0.y) << 16);
    pv.y = (u32)f2bf(f0.z) | ((u32)f2bf(f0.w) << 16);
    pv.z = (u32)f2bf(f1.x) | ((u32)f2bf(f1.y) << 16);
    pv.w = (u32)f2bf(f1.z) | ((u32)f2bf(f1.w) << 16);
    Wl4[o4] = pv;
  }
  {
    const float4* og = (const float4*)(o + (size_t)nb * 128);
#pragma unroll
    for (int i = 0; i < 4; ++i) {
      int idx = tid + 256 * i;
      int row = idx >> 5, part = idx & 31;
      float4 v = make_float4(0.f, 0.f, 0.f, 0.f);
      if (nb + row < N) v = og[row * 32 + part];
      v.x = fmaxf(v.x, 0.f); v.y = fmaxf(v.y, 0.f);
      v.z = fmaxf(v.z, 0.f); v.w = fmaxf(v.w, 0.f);
      os4[row * 33 + part] = v;
    }
  }
  if (tid < 128) { bl[tid] = bk[tid]; ql[tid] = q[tid]; }
  __syncthreads();

  const int nl = tid >> 3, hd = tid & 7, c0 = hd << 4;
  const float* os = (const float*)os4;
  float acc[16];
#pragma unroll
  for (int j = 0; j < 16; ++j) acc[j] = bl[c0 + j];
#pragma unroll 4
  for (int k = 0; k < 128; ++k) {
    float ov = os[nl * 132 + k];
    uint4 w0 = Wl4[(k << 4) + (hd << 1)];
    uint4 w1 = Wl4[(k << 4) + (hd << 1) + 1];
    acc[0]  += ov * blo(w0.x);  acc[1]  += ov * bhi(w0.x);
    acc[2]  += ov * blo(w0.y);  acc[3]  += ov * bhi(w0.y);
    acc[4]  += ov * blo(w0.z);  acc[5]  += ov * bhi(w0.z);
    acc[6]  += ov * blo(w0.w);  acc[7]  += ov * bhi(w0.w);
    acc[8]  += ov * blo(w1.x);  acc[9]  += ov * bhi(w1.x);
    acc[10] += ov * blo(w1.y);  acc[11] += ov * bhi(w1.y);
    acc[12] += ov * blo(w1.z);  acc[13] += ov * bhi(w1.z);
    acc[14] += ov * blo(w1.w);  acc[15] += ov * bhi(w1.w);
  }
  float p = 0.f;
  if (nb + nl < N) {
#pragma unroll
    for (int j = 0; j < 16; ++j) p += tanhf(acc[j]) * ql[c0 + j];
  }
#pragma unroll
  for (int off = 32; off > 0; off >>= 1) p += __shfl_down(p, off);
  if ((tid & 63) == 0) red[tid >> 6] = p;
  __syncthreads();
  if (tid == 0) atomicAdd(score_slot, red[0] + red[1] + red[2] + red[3]);
}

__global__ void attn_kernel(const float* __restrict__ scores, float* __restrict__ attn,
                            float invN)
{
  if (threadIdx.x == 0) {
#pragma unroll
    for (int t = 0; t < 2; ++t) {
      float s0 = scores[2 * t] * invN, s1 = scores[2 * t + 1] * invN;
      float m = fmaxf(s0, s1);
      float e0 = expf(s0 - m), e1 = expf(s1 - m);
      float inv = 1.f / (e0 + e1);
      attn[2 * t] = e0 * inv; attn[2 * t + 1] = e1 * inv;
    }
  }
}

__global__ __launch_bounds__(256) void bn_stats_kernel(
    const float* __restrict__ o0, const float* __restrict__ o1,
    const float* __restrict__ attn, float* __restrict__ sums, int N, int R)
{
  float a0 = attn[0], a1 = attn[1];
  int f = threadIdx.x & 127, half = threadIdx.x >> 7;
  int rend = min((blockIdx.x + 1) * R, N);
  float s = 0.f, sq = 0.f;
  for (int r = blockIdx.x * R + half; r < rend; r += 2) {
    size_t idx = (size_t)r * 128 + f;
    float c = a0 * fmaxf(o0[idx], 0.f) + a1 * fmaxf(o1[idx], 0.f);
    s += c; sq += c * c;
  }
  __shared__ float sm[2][128];
  __shared__ float sm2[2][128];
  sm[half][f] = s; sm2[half][f] = sq;
  __syncthreads();
  if (half == 0) {
    atomicAdd(&sums[f], s + sm[1][f]);
    atomicAdd(&sums[128 + f], sq + sm2[1][f]);
  }
}

__global__ __launch_bounds__(256) void bn_final_kernel(
    const float* __restrict__ o0, const float* __restrict__ o1,
    const float* __restrict__ attn, const float* __restrict__ sums,
    const float* __restrict__ gamma, const float* __restrict__ beta,
    float* __restrict__ out, int N)
{
  __shared__ float scale[128], shift[128];
  if (threadIdx.x < 128) {
    int f = threadIdx.x;
    float invN = 1.f / (float)N;
    float mu = sums[f] * invN;
    float var = fmaxf(sums[128 + f] * invN - mu * mu, 0.f);
    float rs = rsqrtf(var + 1e-5f);
    float g = gamma[f] * rs;
    scale[f] = g;
    shift[f] = beta[f] - mu * g;
  }
  float a0 = attn[0], a1 = attn[1];
  __syncthreads();
  size_t total = (size_t)N * 128;
  for (size_t base = ((size_t)blockIdx.x * 256 + threadIdx.x) * 8; base < total;
       base += (size_t)gridDim.x * 2048) {
    int f0 = (int)(base & 127);
    float4 p0 = *(const float4*)&o0[base];
    float4 p1 = *(const float4*)&o0[base + 4];
    float4 q0 = *(const float4*)&o1[base];
    float4 q1 = *(const float4*)&o1[base + 4];
    float4 r0, r1;
    r0.x = (a0 * fmaxf(p0.x, 0.f) + a1 * fmaxf(q0.x, 0.f)) * scale[f0 + 0] + shift[f0 + 0];
    r0.y = (a0 * fmaxf(p0.y, 0.f) + a1 * fmaxf(q0.y, 0.f)) * scale[f0 + 1] + shift[f0 + 1];
    r0.z = (a0 * fmaxf(p0.z, 0.f) + a1 * fmaxf(q0.z, 0.f)) * scale[f0 + 2] + shift[f0 + 2];
    r0.w = (a0 * fmaxf(p0.w, 0.f) + a1 * fmaxf(q0.w, 0.f)) * scale[f0 + 3] + shift[f0 + 3];
    r1.x = (a0 * fmaxf(p1.x, 0.f) + a1 * fmaxf(q1.x, 0.f)) * scale[f0 + 4] + shift[f0 + 4];
    r1.y = (a0 * fmaxf(p1.y, 0.f) + a1 * fmaxf(q1.y, 0.f)) * scale[f0 + 5] + shift[f0 + 5];
    r1.z = (a0 * fmaxf(p1.z, 0.f) + a1 * fmaxf(q1.z, 0.f)) * scale[f0 + 6] + shift[f0 + 6];
    r1.w = (a0 * fmaxf(p1.w, 0.f) + a1 * fmaxf(q1.w, 0.f)) * scale[f0 + 7] + shift[f0 + 7];
    *(float4*)&out[base] = r0;
    *(float4*)&out[base + 4] = r1;
  }
}

extern "C" void kernel_launch(void* const* d_in, const int* in_sizes, int n_in,
                              void* d_out, int out_size, void* d_ws, size_t ws_size,
                              hipStream_t stream)
{
  const float* x_a      = (const float*)d_in[0];
  const float* x_b      = (const float*)d_in[1];
  const int* ei_ab      = (const int*)d_in[2];
  const int* ei_ba      = (const int*)d_in[3];
  const int* ei_aa      = (const int*)d_in[4];
  const int* ei_bb      = (const int*)d_in[5];
  const float* W_a      = (const float*)d_in[6];
  const float* b_a      = (const float*)d_in[7];
  const float* W_b      = (const float*)d_in[8];
  const float* b_b      = (const float*)d_in[9];
  const float* att_ab_s = (const float*)d_in[10];
  const float* att_ab_d = (const float*)d_in[11];
  const float* att_ba_s = (const float*)d_in[12];
  const float* att_ba_d = (const float*)d_in[13];
  const float* att_aa_s = (const float*)d_in[14];
  const float* att_aa_d = (const float*)d_in[15];
  const float* att_bb_s = (const float*)d_in[16];
  const float* att_bb_d = (const float*)d_in[17];
  const float* Wk       = (const float*)d_in[18];
  const float* bk       = (const float*)d_in[19];
  const float* q        = (const float*)d_in[20];
  const float* gamma    = (const float*)d_in[21];
  const float* beta     = (const float*)d_in[22];

  const int N = in_sizes[0] / 128;
  const int E = in_sizes[2] / 2;

  char* wp = (char*)d_ws;
  auto alloc = [&](size_t bytes) -> void* {
    void* p = (void*)wp;
    wp += (bytes + 255) & ~(size_t)255;
    return p;
  };
  u16* h_a = (u16*)alloc((size_t)N * 128 * 2);
  u16* h_b = (u16*)alloc((size_t)N * 128 * 2);
  float* A[8];
  for (int i = 0; i < 8; ++i) A[i] = (float*)alloc((size_t)N * 8 * 4);
  int* off    = (int*)alloc((size_t)4 * N * 4);
  int* cursor = (int*)alloc((size_t)4 * N * 4);
  int* bsum   = (int*)alloc(1024);
  int* ssrc   = (int*)alloc((size_t)4 * E * 4);
  float* o_ab = (float*)alloc((size_t)N * 128 * 4);
  float* o_ba = (float*)alloc((size_t)N * 128 * 4);
  float* o_aa = (float*)alloc((size_t)N * 128 * 4);
  float* o_bb = (float*)alloc((size_t)N * 128 * 4);
  float* scores = (float*)alloc(16);
  float* attn   = (float*)alloc(16);
  float* sums_a = (float*)alloc(1024);
  float* sums_b = (float*)alloc(1024);
  if ((size_t)(wp - (char*)d_ws) > ws_size) return;

  hipMemsetAsync(off, 0, (size_t)4 * N * 4, stream);
  hipMemsetAsync(scores, 0, 2560, stream);   // scores+attn+sums (contiguous)

  // --- projections (relation order for CSR/aggregate: 0=ab 1=ba 2=aa 3=bb) ---
  const int gproj = (N + 31) / 32;
  proj_kernel<<<gproj, 256, 0, stream>>>(x_a, W_a, b_a, att_ab_s, att_aa_s, att_aa_d,
                                         att_ba_d, h_a, A[0], A[1], A[2], A[3], N);
  proj_kernel<<<gproj, 256, 0, stream>>>(x_b, W_b, b_b, att_ab_d, att_bb_s, att_bb_d,
                                         att_ba_s, h_b, A[4], A[5], A[6], A[7], N);

  // --- CSR build over concatenated 4N dst-counts ---
  const int gE = (E + 255) / 256;
  hist_kernel<<<gE, 256, 0, stream>>>(ei_ab + E, E, off + 0 * N);
  hist_kernel<<<gE, 256, 0, stream>>>(ei_ba + E, E, off + 1 * N);
  hist_kernel<<<gE, 256, 0, stream>>>(ei_aa + E, E, off + 2 * N);
  hist_kernel<<<gE, 256, 0, stream>>>(ei_bb + E, E, off + 3 * N);
  const int M = 4 * N;
  const int G1 = (M + 2047) / 2048;          // <= 256 for N <= 131072
  scan1_kernel<<<G1, 256, 0, stream>>>(off, M, bsum);
  scan2_kernel<<<1, 256, 0, stream>>>(bsum, G1);
  scan3_kernel<<<G1, 256, 0, stream>>>(off, bsum, M, cursor);
  dim3 gsc(gE, 4);
  scatter_kernel<<<gsc, 256, 0, stream>>>(ei_ab, ei_ba, ei_aa, ei_bb, E, N, cursor, ssrc);

  // --- fused softmax + aggregate (1 wave per dst node) ---
  dim3 gag((N + 3) / 4, 4);
  aggregate_kernel<<<gag, 256, 0, stream>>>(
      off, ssrc,
      A[0], A[7], A[1], A[5],          // aS per relation: ab,ba,aa,bb
      A[4], A[3], A[2], A[6],          // aD per relation
      h_a, h_b, h_a, h_b,
      o_ab, o_ba, o_aa, o_bb, N, E);

  // --- semantic attention ---
  sem_score_kernel<<<gproj, 256, 0, stream>>>(o_ba, Wk, bk, q, scores + 0, N);
  sem_score_kernel<<<gproj, 256, 0, stream>>>(o_aa, Wk, bk, q, scores + 1, N);
  sem_score_kernel<<<gproj, 256, 0, stream>>>(o_ab, Wk, bk, q, scores + 2, N);
  sem_score_kernel<<<gproj, 256, 0, stream>>>(o_bb, Wk, bk, q, scores + 3, N);
  attn_kernel<<<1, 64, 0, stream>>>(scores, attn, 1.0f / (float)N);

  // --- batchnorm ---
  const int R = (N + 255) / 256;
  bn_stats_kernel<<<256, 256, 0, stream>>>(o_ba, o_aa, attn + 0, sums_a, N, R);
  bn_stats_kernel<<<256, 256, 0, stream>>>(o_ab, o_bb, attn + 2, sums_b, N, R);

  float* out = (float*)d_out;
  bn_final_kernel<<<2048, 256, 0, stream>>>(o_ba, o_aa, attn + 0, sums_a, gamma, beta,
                                            out, N);
  bn_final_kernel<<<2048, 256, 0, stream>>>(o_ab, o_bb, attn + 2, sums_b, gamma, beta,
                                            out + (size_t)N * 128, N);
}